// Round 1
// baseline (160.581 us; speedup 1.0000x reference)
//
#include <hip/hip_runtime.h>
#include <math.h>

#define BS    128
#define NE    512
#define F     6
#define NH    4
#define DPH   4
#define NEMBD 16

// ---------------------------------------------------------------------------
// Kernel 1: per (batch, head) attention. One thread per query row.
// K/V/bias staged in LDS (18 KB). Two-pass softmax with dot recompute.
// ---------------------------------------------------------------------------
__global__ __launch_bounds__(NE) void attn_kernel(
    const float* __restrict__ inp, const float* __restrict__ mask,
    const float* __restrict__ Wq, const float* __restrict__ Wk,
    const float* __restrict__ Wv, float* __restrict__ att_out)
{
    const int blk = blockIdx.x;
    const int b = blk >> 2;
    const int h = blk & 3;
    const int i = threadIdx.x;

    __shared__ float4 sk[NE];
    __shared__ float4 sv[NE];
    __shared__ float  sb[NE];

    const float mi = mask[b * NE + i];
    const float* row = inp + ((size_t)(b * NE + i)) * F;
    const float x0 = row[0] * mi, x1 = row[1] * mi, x2 = row[2] * mi,
                x3 = row[3] * mi, x4 = row[4] * mi, x5 = row[5] * mi;

    // head-h weight rows (block-uniform -> scalar loads)
    const float* wq = Wq + h * DPH * F;
    const float* wk = Wk + h * DPH * F;
    const float* wv = Wv + h * DPH * F;

    float q[DPH], kk[DPH], vv[DPH];
    #pragma unroll
    for (int d = 0; d < DPH; ++d) {
        const float* w = wq + d * F;
        q[d] = 0.5f * (x0*w[0] + x1*w[1] + x2*w[2] + x3*w[3] + x4*w[4] + x5*w[5]);
        w = wk + d * F;
        kk[d] = x0*w[0] + x1*w[1] + x2*w[2] + x3*w[3] + x4*w[4] + x5*w[5];
        w = wv + d * F;
        vv[d] = x0*w[0] + x1*w[1] + x2*w[2] + x3*w[3] + x4*w[4] + x5*w[5];
    }
    sk[i] = make_float4(kk[0], kk[1], kk[2], kk[3]);
    sv[i] = make_float4(vv[0], vv[1], vv[2], vv[3]);
    sb[i] = (mi - 1.0f) * 1e9f;   // additive key bias, exactly as reference
    __syncthreads();

    // pass 1: row max (includes -1e9 bias, matching reference semantics)
    float m = -3.0e38f;
    #pragma unroll 4
    for (int j = 0; j < NE; ++j) {
        const float4 kv = sk[j];
        const float s = fmaf(q[0], kv.x, fmaf(q[1], kv.y,
                        fmaf(q[2], kv.z, fmaf(q[3], kv.w, sb[j]))));
        m = fmaxf(m, s);
    }

    // pass 2: exp + weighted-V accumulate (masked keys underflow to exactly 0)
    float l = 0.f, a0 = 0.f, a1 = 0.f, a2 = 0.f, a3 = 0.f;
    #pragma unroll 4
    for (int j = 0; j < NE; ++j) {
        const float4 kv = sk[j];
        const float s = fmaf(q[0], kv.x, fmaf(q[1], kv.y,
                        fmaf(q[2], kv.z, fmaf(q[3], kv.w, sb[j]))));
        const float e = __expf(s - m);
        const float4 uv = sv[j];
        l += e;
        a0 = fmaf(e, uv.x, a0);
        a1 = fmaf(e, uv.y, a1);
        a2 = fmaf(e, uv.z, a2);
        a3 = fmaf(e, uv.w, a3);
    }

    // p = softmax(...) * mask_query  ->  att row scaled by mi / l
    const float r = mi / l;
    float4* o = (float4*)(att_out + ((size_t)(b * NE + i)) * NEMBD + h * DPH);
    *o = make_float4(a0 * r, a1 * r, a2 * r, a3 * r);
}

// ---------------------------------------------------------------------------
// Kernel 2: per-batch epilogue: post-proj + residual, mask-corrected
// normalization, masked mean pool. One thread per entity.
// ---------------------------------------------------------------------------
__global__ __launch_bounds__(NE) void epi_kernel(
    const float* __restrict__ inp, const float* __restrict__ mask,
    const float* __restrict__ Wpost, const float* __restrict__ att,
    float* __restrict__ out)
{
    const int b = blockIdx.x;
    const int i = threadIdx.x;
    const int wave = i >> 6;
    const int lane = i & 63;

    __shared__ float swp[F * NEMBD];   // 96
    __shared__ float red[64];

    if (i < F * NEMBD) swp[i] = Wpost[i];
    __syncthreads();

    const float mi = mask[b * NE + i];
    const float* row = inp + ((size_t)(b * NE + i)) * F;
    const float* ar  = att + ((size_t)(b * NE + i)) * NEMBD;

    float a[NEMBD];
    #pragma unroll
    for (int t = 0; t < NEMBD; t += 4) {
        const float4 v = *(const float4*)(ar + t);
        a[t] = v.x; a[t+1] = v.y; a[t+2] = v.z; a[t+3] = v.w;
    }

    float x[F];
    #pragma unroll
    for (int f = 0; f < F; ++f) {
        float acc = row[f] * mi;                  // x_in (residual)
        #pragma unroll
        for (int t = 0; t < NEMBD; ++t) acc = fmaf(a[t], swp[f * NEMBD + t], acc);
        x[f] = acc;
    }

    // ---- phase 1: reduce S = sum(x), N = sum(mask) ----
    float rs = x[0] + x[1] + x[2] + x[3] + x[4] + x[5];
    float rn = mi;
    #pragma unroll
    for (int off = 32; off >= 1; off >>= 1) {
        rs += __shfl_down(rs, off);
        rn += __shfl_down(rn, off);
    }
    if (lane == 0) { red[wave * 2] = rs; red[wave * 2 + 1] = rn; }
    __syncthreads();
    float S = 0.f, N = 0.f;
    #pragma unroll
    for (int w = 0; w < 8; ++w) { S += red[w * 2]; N += red[w * 2 + 1]; }

    const float mu     = S / (6.0f * N);                     // mean(x)*(ne/N)
    const float sum_x2 = S + (NE - N) * 6.0f * mu;           // sum(x2)
    const float m2     = sum_x2 / (NE * 6.0f);
    const float add    = (1.0f - mi) * mu;                   // x2 = x + (1-mask)*mu

    float ss = 0.f;
    #pragma unroll
    for (int f = 0; f < F; ++f) { const float d = x[f] + add - m2; ss = fmaf(d, d, ss); }

    // ---- phase 2: reduce sum((x2-m2)^2) ----
    __syncthreads();   // protect red before reuse
    #pragma unroll
    for (int off = 32; off >= 1; off >>= 1) ss += __shfl_down(ss, off);
    if (lane == 0) red[wave] = ss;
    __syncthreads();
    float vs = 0.f;
    #pragma unroll
    for (int w = 0; w < 8; ++w) vs += red[w];

    const float var  = vs / (NE * 6.0f - 1.0f);
    const float stdv = sqrtf(var) * sqrtf((6.0f * NE - 1.0f) / (6.0f * N - 1.0f));
    const float inv  = 1.0f / (stdv + 1e-6f);

    float y[F];
    #pragma unroll
    for (int f = 0; f < F; ++f) y[f] = mi * (x[f] - mu) * inv;

    // ---- phase 3: reduce 6 masked feature sums ----
    __syncthreads();   // protect red before reuse
    #pragma unroll
    for (int off = 32; off >= 1; off >>= 1) {
        #pragma unroll
        for (int f = 0; f < F; ++f) y[f] += __shfl_down(y[f], off);
    }
    if (lane == 0) {
        #pragma unroll
        for (int f = 0; f < F; ++f) red[wave * F + f] = y[f];
    }
    __syncthreads();
    if (i < F) {
        float t = 0.f;
        #pragma unroll
        for (int w = 0; w < 8; ++w) t += red[w * F + i];
        out[b * F + i] = t / N;
    }
}

// ---------------------------------------------------------------------------
extern "C" void kernel_launch(void* const* d_in, const int* in_sizes, int n_in,
                              void* d_out, int out_size, void* d_ws, size_t ws_size,
                              hipStream_t stream) {
    const float* inp   = (const float*)d_in[0];
    const float* mask  = (const float*)d_in[1];
    const float* Wq    = (const float*)d_in[2];
    const float* Wk    = (const float*)d_in[3];
    const float* Wv    = (const float*)d_in[4];
    const float* Wpost = (const float*)d_in[5];
    float* out = (float*)d_out;
    float* att = (float*)d_ws;   // BS*NE*NEMBD floats = 4 MB

    attn_kernel<<<BS * NH, NE, 0, stream>>>(inp, mask, Wq, Wk, Wv, att);
    epi_kernel<<<BS, NE, 0, stream>>>(inp, mask, Wpost, att, out);
}

// Round 2
// 108.838 us; speedup vs baseline: 1.4754x; 1.4754x over previous
//
#include <hip/hip_runtime.h>
#include <math.h>

#define BS    128
#define NE    512
#define F     6
#define NH    4
#define DPH   4
#define NEMBD 16

// chunk-padded LDS layout: 4 chunks of 128 entities, +1 float4 pad per chunk
// so the 4 concurrent chunk addresses in a wave land on disjoint bank groups.
#define CPAD 129   // float4 elements per chunk slot

// ---------------------------------------------------------------------------
// attn v2: block=(b,h), 512 threads. thread t: chunk c=t&3 (128 keys),
// rows 4g..4g+3 (g=t>>2). Single-pass no-max softmax. Masked entities have
// k=v=0 exactly -> e=1, v-contribution=0 -> correct l by subtracting (512-N).
// Partials combined across the lane quad via __shfl_xor.
// ---------------------------------------------------------------------------
__global__ __launch_bounds__(512) void attn_kernel(
    const float* __restrict__ inp, const float* __restrict__ mask,
    const float* __restrict__ Wq, const float* __restrict__ Wk,
    const float* __restrict__ Wv, float* __restrict__ att_out)
{
    const int blk = blockIdx.x;
    const int b = blk >> 2;
    const int h = blk & 3;
    const int t = threadIdx.x;
    const int c = t & 3;          // j-chunk
    const int g = t >> 2;         // row group: rows 4g..4g+3

    __shared__ float4 sk[4 * CPAD];
    __shared__ float4 sv[4 * CPAD];
    __shared__ float  sn[8];      // per-wave mask sums

    // ---- staging: thread t computes K/V for entity e=t ----
    {
        const int e = t;
        const float me = mask[b * NE + e];
        const float2* rp = (const float2*)(inp + ((size_t)(b * NE + e)) * F);
        const float2 r0 = rp[0], r1 = rp[1], r2 = rp[2];
        const float x0 = r0.x * me, x1 = r0.y * me, x2 = r1.x * me,
                    x3 = r1.y * me, x4 = r2.x * me, x5 = r2.y * me;
        const float* wk = Wk + h * DPH * F;
        const float* wv = Wv + h * DPH * F;
        float kk[DPH], vv[DPH];
        #pragma unroll
        for (int d = 0; d < DPH; ++d) {
            const float* w = wk + d * F;
            kk[d] = x0*w[0] + x1*w[1] + x2*w[2] + x3*w[3] + x4*w[4] + x5*w[5];
            w = wv + d * F;
            vv[d] = x0*w[0] + x1*w[1] + x2*w[2] + x3*w[3] + x4*w[4] + x5*w[5];
        }
        const int ce = e >> 7, je = e & 127;
        sk[ce * CPAD + je] = make_float4(kk[0], kk[1], kk[2], kk[3]);
        sv[ce * CPAD + je] = make_float4(vv[0], vv[1], vv[2], vv[3]);

        // block mask sum N (for l correction): wave reduce then LDS
        float mw = me;
        #pragma unroll
        for (int off = 32; off >= 1; off >>= 1) mw += __shfl_down(mw, off);
        if ((t & 63) == 0) sn[t >> 6] = mw;
    }

    // ---- q for this thread's 4 rows (redundant x4 across the quad; cheap) ----
    float q[4][DPH];
    {
        const float* wq = Wq + h * DPH * F;
        #pragma unroll
        for (int r = 0; r < 4; ++r) {
            const int row = 4 * g + r;
            const float mr = mask[b * NE + row];
            const float2* rp = (const float2*)(inp + ((size_t)(b * NE + row)) * F);
            const float2 r0 = rp[0], r1 = rp[1], r2 = rp[2];
            const float x0 = r0.x * mr, x1 = r0.y * mr, x2 = r1.x * mr,
                        x3 = r1.y * mr, x4 = r2.x * mr, x5 = r2.y * mr;
            #pragma unroll
            for (int d = 0; d < DPH; ++d) {
                const float* w = wq + d * F;
                q[r][d] = 0.5f * (x0*w[0] + x1*w[1] + x2*w[2] + x3*w[3] + x4*w[4] + x5*w[5]);
            }
        }
    }

    __syncthreads();

    float Nb = 0.f;
    #pragma unroll
    for (int w = 0; w < 8; ++w) Nb += sn[w];
    const float lcorr = 512.0f - Nb;   // exact: masked entities contribute e=1

    // ---- inner loop: 128 keys of chunk c, 4 rows ----
    const float4* kbase = sk + c * CPAD;
    const float4* vbase = sv + c * CPAD;
    float l[4] = {0.f, 0.f, 0.f, 0.f};
    float a[4][DPH];
    #pragma unroll
    for (int r = 0; r < 4; ++r)
        #pragma unroll
        for (int d = 0; d < DPH; ++d) a[r][d] = 0.f;

    #pragma unroll 4
    for (int jj = 0; jj < 128; ++jj) {
        const float4 kv = kbase[jj];
        const float4 uv = vbase[jj];
        #pragma unroll
        for (int r = 0; r < 4; ++r) {
            const float s = fmaf(q[r][0], kv.x, fmaf(q[r][1], kv.y,
                             fmaf(q[r][2], kv.z, q[r][3] * kv.w)));
            const float e = __expf(s);
            l[r] += e;
            a[r][0] = fmaf(e, uv.x, a[r][0]);
            a[r][1] = fmaf(e, uv.y, a[r][1]);
            a[r][2] = fmaf(e, uv.z, a[r][2]);
            a[r][3] = fmaf(e, uv.w, a[r][3]);
        }
    }

    // ---- butterfly over the lane quad (chunks) ----
    #pragma unroll
    for (int m = 1; m <= 2; m <<= 1) {
        #pragma unroll
        for (int r = 0; r < 4; ++r) {
            l[r] += __shfl_xor(l[r], m);
            #pragma unroll
            for (int d = 0; d < DPH; ++d) a[r][d] += __shfl_xor(a[r][d], m);
        }
    }

    // ---- thread writes row 4g+c using its r=c slot ----
    const int row = 4 * g + c;
    const float mi = mask[b * NE + row];
    const float lr = l[c] - lcorr;
    const float rscale = mi / lr;
    float4* o = (float4*)(att_out + ((size_t)(b * NE + row)) * NEMBD + h * DPH);
    *o = make_float4(a[c][0] * rscale, a[c][1] * rscale,
                     a[c][2] * rscale, a[c][3] * rscale);
}

// ---------------------------------------------------------------------------
// epilogue: unchanged from round 1 (correct); revisit if it dominates.
// ---------------------------------------------------------------------------
__global__ __launch_bounds__(NE) void epi_kernel(
    const float* __restrict__ inp, const float* __restrict__ mask,
    const float* __restrict__ Wpost, const float* __restrict__ att,
    float* __restrict__ out)
{
    const int b = blockIdx.x;
    const int i = threadIdx.x;
    const int wave = i >> 6;
    const int lane = i & 63;

    __shared__ float swp[F * NEMBD];
    __shared__ float red[64];

    if (i < F * NEMBD) swp[i] = Wpost[i];
    __syncthreads();

    const float mi = mask[b * NE + i];
    const float* row = inp + ((size_t)(b * NE + i)) * F;
    const float* ar  = att + ((size_t)(b * NE + i)) * NEMBD;

    float a[NEMBD];
    #pragma unroll
    for (int t = 0; t < NEMBD; t += 4) {
        const float4 v = *(const float4*)(ar + t);
        a[t] = v.x; a[t+1] = v.y; a[t+2] = v.z; a[t+3] = v.w;
    }

    float x[F];
    #pragma unroll
    for (int f = 0; f < F; ++f) {
        float acc = row[f] * mi;
        #pragma unroll
        for (int t = 0; t < NEMBD; ++t) acc = fmaf(a[t], swp[f * NEMBD + t], acc);
        x[f] = acc;
    }

    float rs = x[0] + x[1] + x[2] + x[3] + x[4] + x[5];
    float rn = mi;
    #pragma unroll
    for (int off = 32; off >= 1; off >>= 1) {
        rs += __shfl_down(rs, off);
        rn += __shfl_down(rn, off);
    }
    if (lane == 0) { red[wave * 2] = rs; red[wave * 2 + 1] = rn; }
    __syncthreads();
    float S = 0.f, N = 0.f;
    #pragma unroll
    for (int w = 0; w < 8; ++w) { S += red[w * 2]; N += red[w * 2 + 1]; }

    const float mu     = S / (6.0f * N);
    const float sum_x2 = S + (NE - N) * 6.0f * mu;
    const float m2     = sum_x2 / (NE * 6.0f);
    const float add    = (1.0f - mi) * mu;

    float ss = 0.f;
    #pragma unroll
    for (int f = 0; f < F; ++f) { const float d = x[f] + add - m2; ss = fmaf(d, d, ss); }

    __syncthreads();
    #pragma unroll
    for (int off = 32; off >= 1; off >>= 1) ss += __shfl_down(ss, off);
    if (lane == 0) red[wave] = ss;
    __syncthreads();
    float vs = 0.f;
    #pragma unroll
    for (int w = 0; w < 8; ++w) vs += red[w];

    const float var  = vs / (NE * 6.0f - 1.0f);
    const float stdv = sqrtf(var) * sqrtf((6.0f * NE - 1.0f) / (6.0f * N - 1.0f));
    const float inv  = 1.0f / (stdv + 1e-6f);

    float y[F];
    #pragma unroll
    for (int f = 0; f < F; ++f) y[f] = mi * (x[f] - mu) * inv;

    __syncthreads();
    #pragma unroll
    for (int off = 32; off >= 1; off >>= 1) {
        #pragma unroll
        for (int f = 0; f < F; ++f) y[f] += __shfl_down(y[f], off);
    }
    if (lane == 0) {
        #pragma unroll
        for (int f = 0; f < F; ++f) red[wave * F + f] = y[f];
    }
    __syncthreads();
    if (i < F) {
        float t = 0.f;
        #pragma unroll
        for (int w = 0; w < 8; ++w) t += red[w * F + i];
        out[b * F + i] = t / N;
    }
}

// ---------------------------------------------------------------------------
extern "C" void kernel_launch(void* const* d_in, const int* in_sizes, int n_in,
                              void* d_out, int out_size, void* d_ws, size_t ws_size,
                              hipStream_t stream) {
    const float* inp   = (const float*)d_in[0];
    const float* mask  = (const float*)d_in[1];
    const float* Wq    = (const float*)d_in[2];
    const float* Wk    = (const float*)d_in[3];
    const float* Wv    = (const float*)d_in[4];
    const float* Wpost = (const float*)d_in[5];
    float* out = (float*)d_out;
    float* att = (float*)d_ws;   // BS*NE*NEMBD floats = 4 MB

    attn_kernel<<<BS * NH, NE, 0, stream>>>(inp, mask, Wq, Wk, Wv, att);
    epi_kernel<<<BS, NE, 0, stream>>>(inp, mask, Wpost, att, out);
}